// Round 1
// baseline (309.395 us; speedup 1.0000x reference)
//
#include <hip/hip_runtime.h>

// Problem constants (from reference): B=32, L=2, F=65536, D=768
#define BB 32
#define LL 2
#define FF 65536
#define DD 768
#define F4 (FF / 4)      // 16384 groups of 4 f
#define LD (LL * DD)     // 1536
#define LD4 (LD / 4)     // 384
#define D4 (DD / 4)      // 192

#define FMA4(A, W, S)                                                          \
    do {                                                                       \
        (A).x = fmaf((W).x, (S), (A).x);                                       \
        (A).y = fmaf((W).y, (S), (A).y);                                       \
        (A).z = fmaf((W).z, (S), (A).z);                                       \
        (A).w = fmaf((W).w, (S), (A).w);                                       \
    } while (0)

// Stage 1: partial GEMM over an F-chunk.
// grid = (6, NF); block = 64 (one wave).
// blockIdx.x = column tile: l = ct/3, dtile = ct%3 (256 d each).
// blockIdx.y = F-chunk index c; chunk covers groups [c*chunk4, (c+1)*chunk4).
// partials layout: [c][b][l*768 + dt*256 + lane*4]  (NF x B x 1536 floats)
__global__ __launch_bounds__(64) void cc_stage1(
    const float* __restrict__ f,        // B x F
    const float* __restrict__ weight,   // L x F x D
    float* __restrict__ partials,       // NF x B x LD
    int chunk4)
{
    const int lane = threadIdx.x;       // 0..63
    const int ct   = blockIdx.x;        // 0..5
    const int c    = blockIdx.y;        // chunk
    const int l    = ct / 3;
    const int dt   = ct % 3;

    // weight as float4: index = l*F*D4 + fi*D4 + dt*64 + lane
    const float4* __restrict__ w4p =
        (const float4*)weight + (size_t)l * FF * D4 + (size_t)dt * 64 + lane;
    const float4* __restrict__ f4p = (const float4*)f;   // B x F4

    int g0 = c * chunk4;
    int g1 = g0 + chunk4;
    if (g1 > F4) g1 = F4;

    float4 acc[BB];
#pragma unroll
    for (int b = 0; b < BB; ++b) acc[b] = make_float4(0.f, 0.f, 0.f, 0.f);

    for (int g = g0; g < g1; ++g) {
        const size_t fi = (size_t)g * 4;
        // 4 f-rows of the weight tile: 4 coalesced 1KB wave loads
        float4 w0 = w4p[(fi + 0) * D4];
        float4 w1 = w4p[(fi + 1) * D4];
        float4 w2 = w4p[(fi + 2) * D4];
        float4 w3 = w4p[(fi + 3) * D4];
#pragma unroll
        for (int b = 0; b < BB; ++b) {
            // wave-uniform load of f[b][4g..4g+3] (scalarizable)
            float4 fv = f4p[(size_t)b * F4 + g];
            FMA4(acc[b], w0, fv.x);
            FMA4(acc[b], w1, fv.y);
            FMA4(acc[b], w2, fv.z);
            FMA4(acc[b], w3, fv.w);
        }
    }

    // write partial tile: one float4 per b, coalesced across the wave
    float4* __restrict__ out4 =
        (float4*)partials + (size_t)c * BB * LD4 + (size_t)(l * 192 + dt * 64 + lane);
#pragma unroll
    for (int b = 0; b < BB; ++b)
        out4[(size_t)b * LD4] = acc[b];
}

// Stage 2: out[b, ld] = bias[ld] + sum_c partials[c][b][ld]
__global__ __launch_bounds__(256) void cc_stage2(
    const float* __restrict__ partials,
    const float* __restrict__ bias,
    float* __restrict__ out,
    int nf)
{
    int o = blockIdx.x * 256 + threadIdx.x;   // 0 .. B*LD-1
    if (o >= BB * LD) return;
    int b  = o / LD;
    int ld = o - b * LD;
    float s = bias[ld];
    const float* __restrict__ p = partials + (size_t)b * LD + ld;
#pragma unroll 4
    for (int c = 0; c < nf; ++c)
        s += p[(size_t)c * (BB * LD)];
    out[o] = s;
}

// Correctness-only fallback if workspace is too small to hold one partial set.
__global__ __launch_bounds__(256) void cc_direct(
    const float* __restrict__ f,
    const float* __restrict__ weight,
    const float* __restrict__ bias,
    float* __restrict__ out)
{
    int o = blockIdx.x * 256 + threadIdx.x;
    if (o >= BB * LD) return;
    int b  = o / LD;
    int ld = o - b * LD;
    int l  = ld / DD;
    int d  = ld - l * DD;
    float s = bias[ld];
    const float* wp = weight + (size_t)l * FF * DD + d;
    const float* fp = f + (size_t)b * FF;
    for (int fi = 0; fi < FF; ++fi)
        s = fmaf(fp[fi], wp[(size_t)fi * DD], s);
    out[o] = s;
}

extern "C" void kernel_launch(void* const* d_in, const int* in_sizes, int n_in,
                              void* d_out, int out_size, void* d_ws, size_t ws_size,
                              hipStream_t stream)
{
    const float* f      = (const float*)d_in[0];   // 32 x 65536
    const float* weight = (const float*)d_in[1];   // 2 x 65536 x 768
    const float* bias   = (const float*)d_in[2];   // 2 x 768
    float* out          = (float*)d_out;           // 32 x 2 x 768

    const size_t chunk_bytes = (size_t)BB * LD * sizeof(float);  // 196608 B
    int nf = (int)(ws_size / chunk_bytes);
    if (nf > 256) nf = 256;

    if (nf < 1) {
        // workspace too small: slow but correct fallback
        cc_direct<<<(BB * LD + 255) / 256, 256, 0, stream>>>(f, weight, bias, out);
        return;
    }

    int chunk4 = (F4 + nf - 1) / nf;        // groups of 4 f per chunk
    nf = (F4 + chunk4 - 1) / chunk4;        // actual number of chunks

    dim3 grid1(6, nf);
    cc_stage1<<<grid1, 64, 0, stream>>>(f, weight, (float*)d_ws, chunk4);
    cc_stage2<<<(BB * LD + 255) / 256, 256, 0, stream>>>(
        (const float*)d_ws, bias, out, nf);
}

// Round 5
// 165.898 us; speedup vs baseline: 1.8650x; 1.8650x over previous
//
#include <hip/hip_runtime.h>

// Problem constants: B=32, L=2, F=65536, D=768
#define BB 32
#define LL 2
#define FF 65536
#define DD 768
#define F4 (FF / 4)        // 16384 groups of 4 f
#define LD (LL * DD)       // 1536
#define LD4 (LD / 4)       // 384
#define D4 (DD / 4)        // 192

#define FT_FLOAT4S ((size_t)F4 * BB)            // 524288 float4 = 8.39 MB
#define FT_BYTES   (FT_FLOAT4S * sizeof(float4))
#define CHUNK_BYTES ((size_t)BB * LD * sizeof(float))  // 196608 B

#define FMA4(A, W, S)                                                          \
    do {                                                                       \
        (A).x = fmaf((W).x, (S), (A).x);                                       \
        (A).y = fmaf((W).y, (S), (A).y);                                       \
        (A).z = fmaf((W).z, (S), (A).z);                                       \
        (A).w = fmaf((W).w, (S), (A).w);                                       \
    } while (0)

// Stage 0: transpose f (B x F) -> fT[g][b] as float4, g in [0,F4), b in [0,32).
// fT4[g*32 + b] = f4[b*F4 + g]. Reads coalesced (t = b*F4 + g, g fastest).
__global__ __launch_bounds__(256) void cc_transpose(
    const float4* __restrict__ f4, float4* __restrict__ fT4)
{
    size_t t = (size_t)blockIdx.x * 256 + threadIdx.x;   // 0 .. F4*32-1
    if (t >= FT_FLOAT4S) return;
    int b = (int)(t / F4);
    int g = (int)(t - (size_t)b * F4);
    fT4[(size_t)g * BB + b] = f4[t];
}

// Stage 1: partial GEMM over an F-chunk.
// grid = (6, NF); block = 64 (one wave).  ct: l = ct/3, dt = ct%3 (256 d each).
// partials[c][b][l*768 + dt*256 + lane*4]
__global__ __launch_bounds__(64, 1) void cc_stage1(
    const float4* __restrict__ fT4,     // [F4][32] float4
    const float* __restrict__ weight,   // L x F x D
    float* __restrict__ partials,       // NF x B x LD
    int chunk4)
{
    const int lane = threadIdx.x;
    const int ct   = blockIdx.x;        // 0..5
    const int c    = blockIdx.y;        // chunk
    const int l    = ct / 3;
    const int dt   = ct - l * 3;

    const float4* __restrict__ w4p =
        (const float4*)weight + (size_t)l * FF * D4 + (size_t)dt * 64 + lane;

    int g0 = c * chunk4;
    int g1 = g0 + chunk4;
    if (g1 > F4) g1 = F4;

    float4 acc[BB];
#pragma unroll
    for (int b = 0; b < BB; ++b) acc[b] = make_float4(0.f, 0.f, 0.f, 0.f);

    // prefetch first iteration's 4 weight rows
    float4 w0 = w4p[((size_t)g0 * 4 + 0) * D4];
    float4 w1 = w4p[((size_t)g0 * 4 + 1) * D4];
    float4 w2 = w4p[((size_t)g0 * 4 + 2) * D4];
    float4 w3 = w4p[((size_t)g0 * 4 + 3) * D4];

    for (int g = g0; g < g1; ++g) {
        // prefetch next iteration (clamped: last iter reloads current, harmless)
        int gn = (g + 1 < g1) ? (g + 1) : g;
        float4 n0 = w4p[((size_t)gn * 4 + 0) * D4];
        float4 n1 = w4p[((size_t)gn * 4 + 1) * D4];
        float4 n2 = w4p[((size_t)gn * 4 + 2) * D4];
        float4 n3 = w4p[((size_t)gn * 4 + 3) * D4];

        const float4* __restrict__ fr = fT4 + (size_t)g * BB;  // wave-uniform, 512B
#pragma unroll
        for (int b = 0; b < BB; ++b) {
            float4 fv = fr[b];
            FMA4(acc[b], w0, fv.x);
            FMA4(acc[b], w1, fv.y);
            FMA4(acc[b], w2, fv.z);
            FMA4(acc[b], w3, fv.w);
        }
        w0 = n0; w1 = n1; w2 = n2; w3 = n3;
    }

    float4* __restrict__ out4 =
        (float4*)partials + (size_t)c * BB * LD4 + (size_t)(l * 192 + dt * 64 + lane);
#pragma unroll
    for (int b = 0; b < BB; ++b)
        out4[(size_t)b * LD4] = acc[b];
}

// Stage 2: out[b, ld] = bias[ld] + sum_c partials[c][b][ld]
__global__ __launch_bounds__(256) void cc_stage2(
    const float* __restrict__ partials,
    const float* __restrict__ bias,
    float* __restrict__ out,
    int nf)
{
    int o = blockIdx.x * 256 + threadIdx.x;   // 0 .. B*LD-1
    if (o >= BB * LD) return;
    int b  = o / LD;
    int ld = o - b * LD;
    float s = bias[ld];
    const float* __restrict__ p = partials + (size_t)b * LD + ld;
#pragma unroll 4
    for (int c = 0; c < nf; ++c)
        s += p[(size_t)c * (BB * LD)];
    out[o] = s;
}

// Correctness-only fallback if workspace is too small.
__global__ __launch_bounds__(256) void cc_direct(
    const float* __restrict__ f,
    const float* __restrict__ weight,
    const float* __restrict__ bias,
    float* __restrict__ out)
{
    int o = blockIdx.x * 256 + threadIdx.x;
    if (o >= BB * LD) return;
    int b  = o / LD;
    int ld = o - b * LD;
    int l  = ld / DD;
    int d  = ld - l * DD;
    float s = bias[ld];
    const float* wp = weight + (size_t)l * FF * DD + d;
    const float* fp = f + (size_t)b * FF;
    for (int fi = 0; fi < FF; ++fi)
        s = fmaf(fp[fi], wp[(size_t)fi * DD], s);
    out[o] = s;
}

extern "C" void kernel_launch(void* const* d_in, const int* in_sizes, int n_in,
                              void* d_out, int out_size, void* d_ws, size_t ws_size,
                              hipStream_t stream)
{
    const float* f      = (const float*)d_in[0];   // 32 x 65536
    const float* weight = (const float*)d_in[1];   // 2 x 65536 x 768
    const float* bias   = (const float*)d_in[2];   // 2 x 768
    float* out          = (float*)d_out;           // 32 x 2 x 768

    if (ws_size < FT_BYTES + CHUNK_BYTES) {
        cc_direct<<<(BB * LD + 255) / 256, 256, 0, stream>>>(f, weight, bias, out);
        return;
    }

    int nf = (int)((ws_size - FT_BYTES) / CHUNK_BYTES);
    if (nf > 256) nf = 256;
    int chunk4 = (F4 + nf - 1) / nf;
    nf = (F4 + chunk4 - 1) / chunk4;

    float4* fT4     = (float4*)d_ws;
    float*  partials = (float*)((char*)d_ws + FT_BYTES);

    cc_transpose<<<(int)((FT_FLOAT4S + 255) / 256), 256, 0, stream>>>(
        (const float4*)f, fT4);

    dim3 grid1(6, nf);
    cc_stage1<<<grid1, 64, 0, stream>>>(fT4, weight, partials, chunk4);

    cc_stage2<<<(BB * LD + 255) / 256, 256, 0, stream>>>(
        partials, bias, out, nf);
}